// Round 6
// baseline (216.844 us; speedup 1.0000x reference)
//
#include <hip/hip_runtime.h>
#include <hip/hip_bf16.h>

// TopKPool: y = X@kn (kn = l2-normalized kernel); idx = sorted top-2048 of y;
// X_pooled = (X*tanh(y))[idx]; A_pooled = A[idx,:] @ A[:,idx]  (== (A@A)[idx][:,idx]);
// S_pooled = S[idx].
// Pipeline: k_score -> k_rank -> k_compact -> {k_gatherAX, k_packB}
//           -> k_gemm (bf16 MFMA, adaptive split-K) -> [k_reduce]

#define NN 4096
#define FF 256
#define KKEEP 2048
#define KDIM 4096

typedef __attribute__((ext_vector_type(8))) short short8;
typedef __attribute__((ext_vector_type(4))) float f32x4;

__device__ __forceinline__ unsigned short f2bf(float x) {
  unsigned u = __float_as_uint(x);
  unsigned r = (u + 0x7FFFu + ((u >> 16) & 1u)) >> 16;   // RTN-even; inputs finite
  return (unsigned short)r;
}

__device__ __forceinline__ void gload_lds16(const void* g, void* l) {
  __builtin_amdgcn_global_load_lds((const __attribute__((address_space(1))) void*)g,
                                   (__attribute__((address_space(3))) void*)l, 16, 0, 0);
}

// ---------- kernel 1: y[i] = dot(X[i,:], kernel)/||kernel|| ----------
__global__ __launch_bounds__(256) void k_score(const float* __restrict__ X,
                                               const float* __restrict__ kern,
                                               float* __restrict__ y) {
  int t = threadIdx.x, lane = t & 63, w = t >> 6;
  int row = blockIdx.x * 4 + w;
  const float4* X4 = (const float4*)(X + (size_t)row * FF);
  const float4* K4 = (const float4*)kern;
  float4 xv = X4[lane];
  float4 kv = K4[lane];
  float p  = xv.x * kv.x + xv.y * kv.y + xv.z * kv.z + xv.w * kv.w;
  float pk = kv.x * kv.x + kv.y * kv.y + kv.z * kv.z + kv.w * kv.w;
  #pragma unroll
  for (int off = 32; off; off >>= 1) {
    p  += __shfl_xor(p, off);
    pk += __shfl_xor(pk, off);
  }
  if (lane == 0) y[row] = p / sqrtf(pk);
}

// ---------- kernel 2: stable top-k selection via rank counting ----------
// rank_i = #{j: y_j > y_i} + #{j<i: y_j == y_i}  (permutation of 0..N-1)
// selected iff rank_i < KKEEP — exactly matches jax.lax.top_k tie semantics.
// 256 blocks x 16 rows; 16 j-segments of 256 per row, one per 16-lane group.
// LDS reads are float4, group-uniform (broadcast); segment offsets staggered
// so concurrent groups alias at worst 2-way (free per m136).
__global__ __launch_bounds__(256) void k_rank(const float* __restrict__ y,
                                              int* __restrict__ sel) {
  __shared__ __align__(16) float ys[NN];
  __shared__ int part[4][16];
  int t = threadIdx.x;
  const float4* Y4 = (const float4*)y;
  float4* ys4 = (float4*)ys;
  #pragma unroll
  for (int k = 0; k < 4; ++k) ys4[t + k * 256] = Y4[t + k * 256];
  __syncthreads();
  int lane = t & 63, w = t >> 6;
  int r = lane & 15;                  // row within block
  int i = blockIdx.x * 16 + r;        // global row
  int seg = w * 4 + (lane >> 4);      // 16 segments of 256 j's
  float yi = ys[i];
  int cnt = 0;
  #pragma unroll 4
  for (int s = 0; s < 64; ++s) {
    int f4 = seg * 64 + ((s + seg * 4) & 63);   // stagger -> 2-way alias max
    float4 v = ys4[f4];
    int j = f4 * 4;
    cnt += (int)((v.x > yi) || (v.x == yi && (j + 0) < i));
    cnt += (int)((v.y > yi) || (v.y == yi && (j + 1) < i));
    cnt += (int)((v.z > yi) || (v.z == yi && (j + 2) < i));
    cnt += (int)((v.w > yi) || (v.w == yi && (j + 3) < i));
  }
  cnt += __shfl_xor(cnt, 16);         // combine 4 segment-groups in wave
  cnt += __shfl_xor(cnt, 32);
  if (lane < 16) part[w][lane] = cnt;
  __syncthreads();
  if (w == 0 && lane < 16) {
    int tot = part[0][lane] + part[1][lane] + part[2][lane] + part[3][lane];
    sel[blockIdx.x * 16 + lane] = (tot < KKEEP) ? 1 : 0;
  }
}

// ---------- kernel 3: compact selected indices (ascending) + S_pooled ----------
__global__ __launch_bounds__(256) void k_compact(const int* __restrict__ sel,
                                                 const int* __restrict__ S32,
                                                 int* __restrict__ idxb,
                                                 float* __restrict__ outSf,
                                                 long long* __restrict__ outSi,
                                                 int smode) {
  __shared__ int sums[256];
  __shared__ int offs[256];
  int t = threadIdx.x;
  int base = t * 16;
  int loc[16];
  int s = 0;
  #pragma unroll
  for (int u = 0; u < 16; ++u) { loc[u] = sel[base + u]; s += loc[u]; }
  sums[t] = s;
  __syncthreads();
  if (t == 0) {
    int acc = 0;
    for (int q = 0; q < 256; ++q) { offs[q] = acc; acc += sums[q]; }
  }
  __syncthreads();
  // If S is int64 on device, the int32 view ends with the high word of the
  // last (sorted, max~15) element == 0. Genuine int32 sorted data ends at max>=1.
  bool in64 = (S32[NN - 1] == 0);
  int pos = offs[t];
  for (int u = 0; u < 16; ++u) {
    if (loc[u]) {
      int gi = base + u;
      idxb[pos] = gi;
      int sval = in64 ? S32[2 * gi] : S32[gi];
      if (smode == 0) outSf[pos] = (float)sval;   // 4-byte slot mode
      else            outSi[pos] = (long long)sval; // 8-byte slot mode
      ++pos;
    }
  }
}

// ---------- kernel 4: fused row-gathers ----------
// Ag[p][k] = bf16(A[idx[p]][k])            (all 262144 threads, 8 float4 each)
// X_pooled[p,:] = X[idx[p],:]*tanh(y[idx[p]])  (threads < 131072, 1 float4 each)
__global__ __launch_bounds__(256) void k_gatherAX(const float* __restrict__ A,
                                                  const float* __restrict__ X,
                                                  const float* __restrict__ y,
                                                  const int* __restrict__ idxb,
                                                  unsigned short* __restrict__ Ag,
                                                  float* __restrict__ outX) {
  int tid = blockIdx.x * 256 + threadIdx.x;  // 262144 threads
  #pragma unroll
  for (int it = 0; it < 8; ++it) {
    int e = tid + it * 262144;               // float4 index, 2097152 total
    int p = e >> 10, c4 = e & 1023;
    int r = idxb[p];
    float4 v = ((const float4*)(A + (size_t)r * NN))[c4];
    ushort4 o;
    o.x = f2bf(v.x); o.y = f2bf(v.y); o.z = f2bf(v.z); o.w = f2bf(v.w);
    ((ushort4*)Ag)[e] = o;
  }
  if (tid < 131072) {                        // 2048 rows x 64 float4
    int p = tid >> 6, c4 = tid & 63;
    int r = idxb[p];
    float ty = tanhf(y[r]);
    float4 v = ((const float4*)(X + (size_t)r * FF))[c4];
    v.x *= ty; v.y *= ty; v.z *= ty; v.w *= ty;
    ((float4*)outX)[tid] = v;
  }
}

// ---------- kernel 5: Bt[q][k] = bf16(A[k][idx[q]])  (column gather + transpose) ----------
__global__ __launch_bounds__(256) void k_packB(const float* __restrict__ A,
                                               const int* __restrict__ idxb,
                                               unsigned short* __restrict__ Bt) {
  __shared__ unsigned short tile[64][66];    // ushort units: both phases <=2-way (free)
  __shared__ int sidx[64];
  int t = threadIdx.x;
  int bk = blockIdx.x & 63;                  // 64 k-tiles
  int bq = blockIdx.x >> 6;                  // 32 q-tiles
  int k0 = bk * 64, q0 = bq * 64;
  if (t < 64) sidx[t] = idxb[q0 + t];
  __syncthreads();
  int j = t & 63, i0 = t >> 6;
  #pragma unroll
  for (int rr = 0; rr < 16; ++rr) {
    int i = i0 + rr * 4;
    float v = A[(size_t)(k0 + i) * NN + sidx[j]];   // semi-dense gather (idx sorted)
    tile[i][j] = f2bf(v);
  }
  __syncthreads();
  int i2 = t & 63, j0 = t >> 6;
  #pragma unroll
  for (int rr = 0; rr < 16; ++rr) {
    int jj = j0 + rr * 4;
    Bt[(size_t)(q0 + jj) * KDIM + k0 + i2] = tile[i2][jj];  // coalesced in k
  }
}

// ---------- kernel 6: Cdst[s][p][q] = sum_{k in seg s} Ag[p][k]*Bt[q][k] ----------
// 128x128 tile, m97 structure; kseg = KDIM/gridDim.z (adaptive split-K).
__global__ __launch_bounds__(256) void k_gemm(const unsigned short* __restrict__ Ag,
                                              const unsigned short* __restrict__ Bt,
                                              float* __restrict__ Cdst, int kseg) {
  __shared__ __align__(16) unsigned short lA[128 * 32];  // 8 KiB
  __shared__ __align__(16) unsigned short lB[128 * 32];  // 8 KiB
  int t = threadIdx.x, lane = t & 63, w = t >> 6;
  int bx = blockIdx.x, by = blockIdx.y, s = blockIdx.z;
  int wm = w >> 1, wn = w & 1;               // 2x2 waves, each 64x64
  int fr = lane & 15, fq = lane >> 4;
  f32x4 zero = {0.f, 0.f, 0.f, 0.f};
  f32x4 acc[4][4];
  #pragma unroll
  for (int mf = 0; mf < 4; ++mf)
    #pragma unroll
    for (int nf = 0; nf < 4; ++nf) acc[mf][nf] = zero;

  int kbeg = s * kseg, kend = kbeg + kseg;
  for (int k0 = kbeg; k0 < kend; k0 += 32) {
    #pragma unroll
    for (int jj = 0; jj < 2; ++jj) {
      int chunk = jj * 4 + w;                // 8 chunks of 1 KiB per 8 KiB tile
      int e = chunk * 64 + lane;
      int r = e >> 2, kk = (e & 3) * 8;      // LDS linear == row-major [128][32]
      gload_lds16(Ag + (size_t)(by * 128 + r) * KDIM + k0 + kk, lA + chunk * 512);
      gload_lds16(Bt + (size_t)(bx * 128 + r) * KDIM + k0 + kk, lB + chunk * 512);
    }
    __syncthreads();
    short8 a[4], b[4];
    #pragma unroll
    for (int mf = 0; mf < 4; ++mf)
      a[mf] = *(const short8*)&lA[(wm * 64 + mf * 16 + fr) * 32 + fq * 8];
    #pragma unroll
    for (int nf = 0; nf < 4; ++nf)
      b[nf] = *(const short8*)&lB[(wn * 64 + nf * 16 + fr) * 32 + fq * 8];
    #pragma unroll
    for (int mf = 0; mf < 4; ++mf)
      #pragma unroll
      for (int nf = 0; nf < 4; ++nf)
        acc[mf][nf] = __builtin_amdgcn_mfma_f32_16x16x32_bf16(a[mf], b[nf], acc[mf][nf], 0, 0, 0);
    __syncthreads();
  }
  float* Cp = Cdst + (size_t)s * KKEEP * KKEEP;
  #pragma unroll
  for (int mf = 0; mf < 4; ++mf)
    #pragma unroll
    for (int nf = 0; nf < 4; ++nf)
      #pragma unroll
      for (int r = 0; r < 4; ++r) {
        int row = by * 128 + wm * 64 + mf * 16 + fq * 4 + r;  // verified C/D layout (m89)
        int col = bx * 128 + wn * 64 + nf * 16 + fr;
        Cp[(size_t)row * KKEEP + col] = acc[mf][nf][r];
      }
}

// ---------- kernel 7: outA = sum_s Cpart[s]  (launched only when nsplit>1) ----------
__global__ __launch_bounds__(256) void k_reduce(const float* __restrict__ Cpart,
                                                float* __restrict__ outA, int nsplit) {
  const size_t Q = (size_t)KKEEP * KKEEP / 4;     // float4 count = 1048576
  size_t e = (size_t)blockIdx.x * 256 + threadIdx.x;
  const float4* P = (const float4*)Cpart;
  float4 o = P[e];
  for (int s = 1; s < nsplit; ++s) {
    float4 v = P[e + (size_t)s * Q];
    o.x += v.x; o.y += v.y; o.z += v.z; o.w += v.w;
  }
  ((float4*)outA)[e] = o;
}

extern "C" void kernel_launch(void* const* d_in, const int* in_sizes, int n_in,
                              void* d_out, int out_size, void* d_ws, size_t ws_size,
                              hipStream_t stream) {
  const float* X    = (const float*)d_in[0];
  const float* A    = (const float*)d_in[1];
  const int*   S32  = (const int*)d_in[2];
  const float* kern = (const float*)d_in[3];

  float* out  = (float*)d_out;
  float* outX = out;                                   // 2048*256
  float* outA = out + 2048 * 256;                      // 2048*2048
  float*      outSf = out + 2048 * 256 + 2048 * 2048;  // S as f32 (values 0..15 exact)
  long long*  outSi = (long long*)((char*)d_out + (size_t)(2048 * 256 + 2048 * 2048) * 4);
  int smode = (out_size == 4722688) ? 1 : 0;           // 4722688 => S occupies 8-byte slots

  char* wsb = (char*)d_ws;
  float* y    = (float*)wsb;                           // 16 KiB
  int*   sel  = (int*)(wsb + 16384);                   // 16 KiB
  int*   idxb = (int*)(wsb + 32768);                   // 8 KiB
  unsigned short* Ag = (unsigned short*)(wsb + 65536);         // 16 MiB
  unsigned short* Bt = Ag + (size_t)KKEEP * KDIM;              // 16 MiB
  float* Cpart = (float*)(Bt + (size_t)KKEEP * KDIM);          // ksplit*16 MiB partials

  // Adaptive split-K by available workspace (ws_size constant per session -> graph-safe).
  const size_t PART = (size_t)KKEEP * KKEEP * 4;       // 16 MiB
  const size_t BASE = 65536 + (size_t)KKEEP * KDIM * 2 * 2;
  int ksplit = 1;
  if (ws_size >= BASE + 4 * PART)      ksplit = 4;     // 1024 blocks ~ m97/m103 regime
  else if (ws_size >= BASE + 2 * PART) ksplit = 2;
  float* gemmDst = (ksplit > 1) ? Cpart : outA;

  hipLaunchKernelGGL(k_score,    dim3(1024),  dim3(256), 0, stream, X, kern, y);
  hipLaunchKernelGGL(k_rank,     dim3(256),   dim3(256), 0, stream, y, sel);
  hipLaunchKernelGGL(k_compact,  dim3(1),     dim3(256), 0, stream, sel, S32, idxb, outSf, outSi, smode);
  hipLaunchKernelGGL(k_gatherAX, dim3(1024),  dim3(256), 0, stream, A, X, y, idxb, Ag, outX);
  hipLaunchKernelGGL(k_packB,    dim3(2048),  dim3(256), 0, stream, A, idxb, Bt);
  hipLaunchKernelGGL(k_gemm,     dim3(16, 16, ksplit), dim3(256), 0, stream,
                     Ag, Bt, gemmDst, KDIM / ksplit);
  if (ksplit > 1)
    hipLaunchKernelGGL(k_reduce, dim3(4096),  dim3(256), 0, stream, Cpart, outA, ksplit);
}

// Round 10
// 186.159 us; speedup vs baseline: 1.1648x; 1.1648x over previous
//
#include <hip/hip_runtime.h>
#include <hip/hip_bf16.h>

// TopKPool: y = X@kn (kn = l2-normalized kernel); idx = sorted top-2048 of y;
// X_pooled = (X*tanh(y))[idx]; A_pooled = A[idx,:] @ A[:,idx]  (== (A@A)[idx][:,idx]);
// S_pooled = S[idx].
// Pipeline: k_score -> k_rank -> k_compact -> {k_gatherAX, k_packB}
//           -> k_gemm2 (bf16 MFMA, 256x128 tile, 3-buf counted-vmcnt pipeline, split-K=2)
//           -> k_reduce

#define NN 4096
#define FF 256
#define KKEEP 2048
#define KDIM 4096

#define BM 256
#define BN 128
#define BK 64
#define LDSBUF 49152      // bytes per buffer: A 32KB + B 16KB

typedef __attribute__((ext_vector_type(8))) short short8;
typedef __attribute__((ext_vector_type(4))) float f32x4;

__device__ __forceinline__ unsigned short f2bf(float x) {
  unsigned u = __float_as_uint(x);
  unsigned r = (u + 0x7FFFu + ((u >> 16) & 1u)) >> 16;   // RTN-even; inputs finite
  return (unsigned short)r;
}

__device__ __forceinline__ void gload_lds16(const void* g, void* l) {
  __builtin_amdgcn_global_load_lds((const __attribute__((address_space(1))) void*)g,
                                   (__attribute__((address_space(3))) void*)l, 16, 0, 0);
}

// ---------- kernel 1: y[i] = dot(X[i,:], kernel)/||kernel|| ----------
__global__ __launch_bounds__(256) void k_score(const float* __restrict__ X,
                                               const float* __restrict__ kern,
                                               float* __restrict__ y) {
  int t = threadIdx.x, lane = t & 63, w = t >> 6;
  int row = blockIdx.x * 4 + w;
  const float4* X4 = (const float4*)(X + (size_t)row * FF);
  const float4* K4 = (const float4*)kern;
  float4 xv = X4[lane];
  float4 kv = K4[lane];
  float p  = xv.x * kv.x + xv.y * kv.y + xv.z * kv.z + xv.w * kv.w;
  float pk = kv.x * kv.x + kv.y * kv.y + kv.z * kv.z + kv.w * kv.w;
  #pragma unroll
  for (int off = 32; off; off >>= 1) {
    p  += __shfl_xor(p, off);
    pk += __shfl_xor(pk, off);
  }
  if (lane == 0) y[row] = p / sqrtf(pk);
}

// ---------- kernel 2: stable top-k selection via rank counting ----------
// rank_i = #{j: y_j > y_i} + #{j<i: y_j == y_i}; selected iff rank < KKEEP
// (exact jax.lax.top_k tie semantics).
__global__ __launch_bounds__(256) void k_rank(const float* __restrict__ y,
                                              int* __restrict__ sel) {
  __shared__ __align__(16) float ys[NN];
  __shared__ int part[4][16];
  int t = threadIdx.x;
  const float4* Y4 = (const float4*)y;
  float4* ys4 = (float4*)ys;
  #pragma unroll
  for (int k = 0; k < 4; ++k) ys4[t + k * 256] = Y4[t + k * 256];
  __syncthreads();
  int lane = t & 63, w = t >> 6;
  int r = lane & 15;                  // row within block
  int i = blockIdx.x * 16 + r;        // global row
  int seg = w * 4 + (lane >> 4);      // 16 segments of 256 j's
  float yi = ys[i];
  int cnt = 0;
  #pragma unroll 4
  for (int s = 0; s < 64; ++s) {
    int f4 = seg * 64 + ((s + seg * 4) & 63);   // stagger -> 2-way alias max
    float4 v = ys4[f4];
    int j = f4 * 4;
    cnt += (int)((v.x > yi) || (v.x == yi && (j + 0) < i));
    cnt += (int)((v.y > yi) || (v.y == yi && (j + 1) < i));
    cnt += (int)((v.z > yi) || (v.z == yi && (j + 2) < i));
    cnt += (int)((v.w > yi) || (v.w == yi && (j + 3) < i));
  }
  cnt += __shfl_xor(cnt, 16);
  cnt += __shfl_xor(cnt, 32);
  if (lane < 16) part[w][lane] = cnt;
  __syncthreads();
  if (w == 0 && lane < 16) {
    int tot = part[0][lane] + part[1][lane] + part[2][lane] + part[3][lane];
    sel[blockIdx.x * 16 + lane] = (tot < KKEEP) ? 1 : 0;
  }
}

// ---------- kernel 3: compact selected indices (ascending) + S_pooled ----------
__global__ __launch_bounds__(256) void k_compact(const int* __restrict__ sel,
                                                 const int* __restrict__ S32,
                                                 int* __restrict__ idxb,
                                                 float* __restrict__ outSf,
                                                 long long* __restrict__ outSi,
                                                 int smode) {
  __shared__ int sums[256];
  __shared__ int offs[256];
  int t = threadIdx.x;
  int base = t * 16;
  int loc[16];
  int s = 0;
  #pragma unroll
  for (int u = 0; u < 16; ++u) { loc[u] = sel[base + u]; s += loc[u]; }
  sums[t] = s;
  __syncthreads();
  if (t == 0) {
    int acc = 0;
    for (int q = 0; q < 256; ++q) { offs[q] = acc; acc += sums[q]; }
  }
  __syncthreads();
  bool in64 = (S32[NN - 1] == 0);    // int64-layout autodetect (sorted, max~15)
  int pos = offs[t];
  for (int u = 0; u < 16; ++u) {
    if (loc[u]) {
      int gi = base + u;
      idxb[pos] = gi;
      int sval = in64 ? S32[2 * gi] : S32[gi];
      if (smode == 0) outSf[pos] = (float)sval;
      else            outSi[pos] = (long long)sval;
      ++pos;
    }
  }
}

// ---------- kernel 4: fused row-gathers (Ag pack + X_pooled) ----------
__global__ __launch_bounds__(256) void k_gatherAX(const float* __restrict__ A,
                                                  const float* __restrict__ X,
                                                  const float* __restrict__ y,
                                                  const int* __restrict__ idxb,
                                                  unsigned short* __restrict__ Ag,
                                                  float* __restrict__ outX) {
  int tid = blockIdx.x * 256 + threadIdx.x;  // 262144 threads
  #pragma unroll
  for (int it = 0; it < 8; ++it) {
    int e = tid + it * 262144;               // float4 index, 2097152 total
    int p = e >> 10, c4 = e & 1023;
    int r = idxb[p];
    float4 v = ((const float4*)(A + (size_t)r * NN))[c4];
    ushort4 o;
    o.x = f2bf(v.x); o.y = f2bf(v.y); o.z = f2bf(v.z); o.w = f2bf(v.w);
    ((ushort4*)Ag)[e] = o;
  }
  if (tid < 131072) {                        // 2048 rows x 64 float4
    int p = tid >> 6, c4 = tid & 63;
    int r = idxb[p];
    float ty = tanhf(y[r]);
    float4 v = ((const float4*)(X + (size_t)r * FF))[c4];
    v.x *= ty; v.y *= ty; v.z *= ty; v.w *= ty;
    ((float4*)outX)[tid] = v;
  }
}

// ---------- kernel 5: Bt[q][k] = bf16(A[k][idx[q]])  (column gather + transpose) ----------
__global__ __launch_bounds__(256) void k_packB(const float* __restrict__ A,
                                               const int* __restrict__ idxb,
                                               unsigned short* __restrict__ Bt) {
  __shared__ unsigned short tile[64][66];
  __shared__ int sidx[64];
  int t = threadIdx.x;
  int bk = blockIdx.x & 63;
  int bq = blockIdx.x >> 6;
  int k0 = bk * 64, q0 = bq * 64;
  if (t < 64) sidx[t] = idxb[q0 + t];
  __syncthreads();
  int j = t & 63, i0 = t >> 6;
  #pragma unroll
  for (int rr = 0; rr < 16; ++rr) {
    int i = i0 + rr * 4;
    float v = A[(size_t)(k0 + i) * NN + sidx[j]];
    tile[i][j] = f2bf(v);
  }
  __syncthreads();
  int i2 = t & 63, j0 = t >> 6;
  #pragma unroll
  for (int rr = 0; rr < 16; ++rr) {
    int jj = j0 + rr * 4;
    Bt[(size_t)(q0 + jj) * KDIM + k0 + i2] = tile[i2][jj];
  }
}

// ---------- staging helper: pre-swizzled global src -> linear LDS dest ----------
// LDS logical layout per region: row-major [rows][64] bf16 (128B rows).
// Read applies phys = logical ^ ((row&7)<<4); physical slot p must hold logical
// p ^ ((row&7)<<4) (involution; swizzle bits 4-6 never touch row bits >=7).
__device__ __forceinline__ void stage_rows(const unsigned short* __restrict__ srcbase,
                                           int rowoff, int koff,
                                           char* ldsregion, int j, int t, int w) {
  int p = j * 8192 + t * 16;                 // physical byte offset in region
  int row = p >> 7;                          // 128B rows
  int l = p ^ ((row & 7) << 4);              // logical byte
  const unsigned short* src = srcbase + (size_t)(rowoff + row) * KDIM + koff + ((l & 127) >> 1);
  gload_lds16(src, ldsregion + j * 8192 + w * 1024);   // wave-uniform base + lane*16
}

// ---------- kernel 6: Cdst[z][p][q] = sum_{k in slice z} Ag[p][k]*Bt[q][k] ----------
// 256x128 tile, 8 waves (4M x 2N), 3-buffer LDS pipeline, counted vmcnt(6),
// T2 swizzle (2-way max on ds_read_b128), T5 setprio around MFMA clusters.
__global__ __launch_bounds__(512, 2) void k_gemm2(const unsigned short* __restrict__ Ag,
                                                  const unsigned short* __restrict__ Bt,
                                                  float* __restrict__ Cdst, int nt) {
  __shared__ __align__(16) unsigned short lds[3 * LDSBUF / 2];   // 144 KB
  int t = threadIdx.x, lane = t & 63, w = t >> 6;
  int bx = blockIdx.x, by = blockIdx.y, z = blockIdx.z;
  int wm = w >> 1, wn = w & 1;               // 4 M-warps x 2 N-warps; 64x64 each
  int fr = lane & 15, fq = lane >> 4;
  int kbase = z * nt * BK;

  f32x4 acc[4][4];
  #pragma unroll
  for (int mf = 0; mf < 4; ++mf)
    #pragma unroll
    for (int nf = 0; nf < 4; ++nf) acc[mf][nf] = f32x4{0.f, 0.f, 0.f, 0.f};

  // Prologue: stage tiles 0 and 1 into buffers 0 and 1 (oldest-first issue order:
  // tile 0's 6 loads fully issued before tile 1's -> in-order vmcnt drain).
  #pragma unroll
  for (int pt = 0; pt < 2; ++pt) {
    char* bufA = (char*)lds + pt * LDSBUF;
    char* bufB = bufA + 32768;
    int koff = kbase + pt * BK;
    stage_rows(Ag, by * BM, koff, bufA, 0, t, w);
    stage_rows(Ag, by * BM, koff, bufA, 1, t, w);
    stage_rows(Ag, by * BM, koff, bufA, 2, t, w);
    stage_rows(Ag, by * BM, koff, bufA, 3, t, w);
    stage_rows(Bt, bx * BN, koff, bufB, 0, t, w);
    stage_rows(Bt, bx * BN, koff, bufB, 1, t, w);
  }

  int cb = 0;                                // buffer holding tile kt (= kt % 3)
  for (int kt = 0; kt < nt; ++kt) {
    // Outstanding at top: tiles kt (6, oldest) + kt+1 (6). vmcnt(6) drains tile kt.
    if (kt == nt - 1) asm volatile("s_waitcnt vmcnt(0)" ::: "memory");
    else              asm volatile("s_waitcnt vmcnt(6)" ::: "memory");
    __builtin_amdgcn_s_barrier();            // all waves' DMAs for tile kt landed

    int sb = cb + 2; if (sb >= 3) sb -= 3;   // stage dest = (kt+2)%3 (free since iter kt-1)
    const char* lA = (const char*)lds + cb * LDSBUF;
    const char* lB = lA + 32768;
    char* sA = (char*)lds + sb * LDSBUF;
    char* sB = sA + 32768;
    bool doStage = (kt + 2) < nt;
    int koff2 = kbase + (kt + 2) * BK;

    #pragma unroll
    for (int ksub = 0; ksub < 2; ++ksub) {
      if (doStage) {
        if (ksub == 0) {
          stage_rows(Ag, by * BM, koff2, sA, 0, t, w);
          stage_rows(Ag, by * BM, koff2, sA, 1, t, w);
          stage_rows(Ag, by * BM, koff2, sA, 2, t, w);
        } else {
          stage_rows(Ag, by * BM, koff2, sA, 3, t, w);
          stage_rows(Bt, bx * BN, koff2, sB, 0, t, w);
          stage_rows(Bt, bx * BN, koff2, sB, 1, t, w);
        }
      }
      short8 a[4], b[4];
      #pragma unroll
      for (int mf = 0; mf < 4; ++mf) {
        int r = wm * 64 + mf * 16 + fr;
        int lb = r * 128 + ksub * 64 + fq * 16;
        int pb = lb ^ ((r & 7) << 4);        // T2 swizzle on read
        a[mf] = *(const short8*)(lA + pb);
      }
      #pragma unroll
      for (int nf = 0; nf < 4; ++nf) {
        int r = wn * 64 + nf * 16 + fr;
        int lb = r * 128 + ksub * 64 + fq * 16;
        int pb = lb ^ ((r & 7) << 4);
        b[nf] = *(const short8*)(lB + pb);
      }
      __builtin_amdgcn_s_setprio(1);
      #pragma unroll
      for (int mf = 0; mf < 4; ++mf)
        #pragma unroll
        for (int nf = 0; nf < 4; ++nf)
          acc[mf][nf] = __builtin_amdgcn_mfma_f32_16x16x32_bf16(a[mf], b[nf], acc[mf][nf], 0, 0, 0);
      __builtin_amdgcn_s_setprio(0);
    }
    // One barrier per K-tile: next iter's DMA targets buf (kt+3)%3 == cb (being
    // read now) -> no wave may issue it until all waves finished this tile's reads.
    __builtin_amdgcn_s_barrier();
    cb = (cb + 1 == 3) ? 0 : cb + 1;
  }

  float* Cp = Cdst + (size_t)z * KKEEP * KKEEP;
  #pragma unroll
  for (int mf = 0; mf < 4; ++mf)
    #pragma unroll
    for (int nf = 0; nf < 4; ++nf)
      #pragma unroll
      for (int rr = 0; rr < 4; ++rr) {
        int row = by * BM + wm * 64 + mf * 16 + fq * 4 + rr;   // verified C/D layout (m89)
        int col = bx * BN + wn * 64 + nf * 16 + fr;
        Cp[(size_t)row * KKEEP + col] = acc[mf][nf][rr];
      }
}

// ---------- kernel 7: outA = sum_s Cpart[s]  (launched only when nsplit>1) ----------
__global__ __launch_bounds__(256) void k_reduce(const float* __restrict__ Cpart,
                                                float* __restrict__ outA, int nsplit) {
  const size_t Q = (size_t)KKEEP * KKEEP / 4;
  size_t e = (size_t)blockIdx.x * 256 + threadIdx.x;
  const float4* P = (const float4*)Cpart;
  float4 o = P[e];
  for (int s = 1; s < nsplit; ++s) {
    float4 v = P[e + (size_t)s * Q];
    o.x += v.x; o.y += v.y; o.z += v.z; o.w += v.w;
  }
  ((float4*)outA)[e] = o;
}

extern "C" void kernel_launch(void* const* d_in, const int* in_sizes, int n_in,
                              void* d_out, int out_size, void* d_ws, size_t ws_size,
                              hipStream_t stream) {
  const float* X    = (const float*)d_in[0];
  const float* A    = (const float*)d_in[1];
  const int*   S32  = (const int*)d_in[2];
  const float* kern = (const float*)d_in[3];

  float* out  = (float*)d_out;
  float* outX = out;                                   // 2048*256
  float* outA = out + 2048 * 256;                      // 2048*2048
  float*      outSf = out + 2048 * 256 + 2048 * 2048;
  long long*  outSi = (long long*)((char*)d_out + (size_t)(2048 * 256 + 2048 * 2048) * 4);
  int smode = (out_size == 4722688) ? 1 : 0;

  char* wsb = (char*)d_ws;
  float* y    = (float*)wsb;                           // 16 KiB
  int*   sel  = (int*)(wsb + 16384);                   // 16 KiB
  int*   idxb = (int*)(wsb + 32768);                   // 8 KiB
  unsigned short* Ag = (unsigned short*)(wsb + 65536);         // 16 MiB
  unsigned short* Bt = Ag + (size_t)KKEEP * KDIM;              // 16 MiB
  float* Cpart = (float*)(Bt + (size_t)KKEEP * KDIM);          // ksplit*16 MiB partials

  const size_t PART = (size_t)KKEEP * KKEEP * 4;       // 16 MiB
  const size_t BASE = 65536 + (size_t)KKEEP * KDIM * 2 * 2;
  int ksplit = (ws_size >= BASE + 2 * PART) ? 2 : 1;   // round-6 run proved ws >= BASE+4*PART
  float* gemmDst = (ksplit > 1) ? Cpart : outA;
  int nt = KDIM / (BK * ksplit);                       // 32 at ksplit=2

  hipLaunchKernelGGL(k_score,    dim3(1024),  dim3(256), 0, stream, X, kern, y);
  hipLaunchKernelGGL(k_rank,     dim3(256),   dim3(256), 0, stream, y, sel);
  hipLaunchKernelGGL(k_compact,  dim3(1),     dim3(256), 0, stream, sel, S32, idxb, outSf, outSi, smode);
  hipLaunchKernelGGL(k_gatherAX, dim3(1024),  dim3(256), 0, stream, A, X, y, idxb, Ag, outX);
  hipLaunchKernelGGL(k_packB,    dim3(2048),  dim3(256), 0, stream, A, idxb, Bt);
  hipLaunchKernelGGL(k_gemm2,    dim3(16, 8, ksplit), dim3(512), 0, stream,
                     Ag, Bt, gemmDst, nt);
  if (ksplit > 1)
    hipLaunchKernelGGL(k_reduce, dim3(4096),  dim3(256), 0, stream, Cpart, outA, ksplit);
}